// Round 7
// baseline (465.484 us; speedup 1.0000x reference)
//
#include <hip/hip_runtime.h>
#include <math.h>

#define NS 65536
#define HD 256
#define NE 8

typedef short bh8 __attribute__((ext_vector_type(8)));   // 8 bf16 (A/B frag)
typedef float f4  __attribute__((ext_vector_type(4)));   // MFMA acc
typedef unsigned short ush;

// Row permutation for A-plane LDS layout: m' = m ^ (m>>2) (involution).
__device__ __forceinline__ int rowperm(int m) { return m ^ (m >> 2); }

// Scheduler fence mask: DS_READ(0x100)|VALU(0x2) may cross; VMEM and MFMA may
// not. Pins B-loads/MFMA ordering while letting A-reads software-pipeline.
#define GEMM_FENCE 0x102

// ---------------------------------------------------------------------------
// LDS-only barrier: __syncthreads() drains vmcnt(0) (compiler-emitted), which
// kills cross-barrier global-load pipelining. Every barrier in these kernels
// guards LDS only, so lgkmcnt(0)+s_barrier is sufficient.
// ---------------------------------------------------------------------------
__device__ __forceinline__ void lds_barrier() {
    asm volatile("s_waitcnt lgkmcnt(0)" ::: "memory");
    __builtin_amdgcn_s_barrier();
    __builtin_amdgcn_sched_barrier(0);
}

// ---------------------------------------------------------------------------
// split helpers. Truncate-hi + RHU-lo: err <= 2^-17|x| (2-way), 2^-25 (3-way).
// ---------------------------------------------------------------------------
__device__ __forceinline__ void split2t(float x, ush& h, ush& l) {
    unsigned u = __float_as_uint(x);
    h = (ush)(u >> 16);
    float lo = x - __uint_as_float(u & 0xffff0000u);
    l = (ush)((__float_as_uint(lo) + 0x8000u) >> 16);
}
__device__ __forceinline__ unsigned pack2t(float x) {     // hi | lo<<16
    ush h, l; split2t(x, h, l);
    return (unsigned)h | ((unsigned)l << 16);
}
__device__ __forceinline__ float unpackf(unsigned p) {    // inverse of pack2t
    return __uint_as_float(p << 16) + __uint_as_float(p & 0xffff0000u);
}
// reconstruct from separate hi/lo plane halves
__device__ __forceinline__ float planes2f(ush h, ush l) {
    return __uint_as_float((unsigned)h << 16) + __uint_as_float((unsigned)l << 16);
}
__device__ __forceinline__ void split3t(float x, ush& h, ush& m, ush& l) {
    unsigned u = __float_as_uint(x);
    h = (ush)(u >> 16);
    float r1 = x - __uint_as_float(u & 0xffff0000u);
    unsigned u1 = __float_as_uint(r1);
    m = (ush)(u1 >> 16);
    float r2 = r1 - __uint_as_float(u1 & 0xffff0000u);
    l = (ush)((__float_as_uint(r2) + 0x8000u) >> 16);
}
// RNE splits for one-time weight preps
__device__ __forceinline__ void bfsplit(float x, ush& h, ush& l) {
    unsigned u  = __float_as_uint(x);
    unsigned hb = (u + 0x7fffu + ((u >> 16) & 1u)) & 0xffff0000u;
    h = (ush)(hb >> 16);
    float    lo = x - __uint_as_float(hb);
    unsigned ul = __float_as_uint(lo);
    l = (ush)((ul + 0x7fffu + ((ul >> 16) & 1u)) >> 16);
}
__device__ __forceinline__ void bfsplit3(float x, ush& h, ush& m, ush& l) {
    unsigned u  = __float_as_uint(x);
    unsigned hb = (u + 0x7fffu + ((u >> 16) & 1u)) & 0xffff0000u;
    h = (ush)(hb >> 16);
    float r1 = x - __uint_as_float(hb);
    unsigned u1 = __float_as_uint(r1);
    unsigned mb = (u1 + 0x7fffu + ((u1 >> 16) & 1u)) & 0xffff0000u;
    m = (ush)(mb >> 16);
    float r2 = r1 - __uint_as_float(mb);
    unsigned u2 = __float_as_uint(r2);
    l = (ush)((u2 + 0x7fffu + ((u2 >> 16) & 1u)) >> 16);
}

// 8 packed uint32 -> hi/lo bh8 planes (used once at expert gather)
__device__ __forceinline__ void unpack8(const unsigned* p, bh8& h, bh8& l) {
    uint4 a = *(const uint4*)p;
    uint4 b = *(const uint4*)(p + 4);
    union { unsigned u[4]; bh8 v; } H, L;
    H.u[0] = __builtin_amdgcn_perm(a.y, a.x, 0x05040100u);
    H.u[1] = __builtin_amdgcn_perm(a.w, a.z, 0x05040100u);
    H.u[2] = __builtin_amdgcn_perm(b.y, b.x, 0x05040100u);
    H.u[3] = __builtin_amdgcn_perm(b.w, b.z, 0x05040100u);
    L.u[0] = __builtin_amdgcn_perm(a.y, a.x, 0x07060302u);
    L.u[1] = __builtin_amdgcn_perm(a.w, a.z, 0x07060302u);
    L.u[2] = __builtin_amdgcn_perm(b.y, b.x, 0x07060302u);
    L.u[3] = __builtin_amdgcn_perm(b.w, b.z, 0x07060302u);
    h = H.v; l = L.v;
}

// B0 prefetch helpers: issue kc=0 B fragments early so they fly across
// epilogue + lgkmcnt-only barriers.
template<int NTW>
__device__ __forceinline__ void loadB0(const ush* __restrict__ Wh, const ush* __restrict__ Wl,
                                       int lane, int ntoff, bh8 nbh[NTW], bh8 nbl[NTW])
{
    #pragma unroll
    for (int nl = 0; nl < NTW; ++nl) {
        const int fo = ((ntoff + nl) * 64 + lane) * 8;
        nbh[nl] = *(const bh8*)(Wh + fo);
        nbl[nl] = *(const bh8*)(Wl + fo);
    }
}
template<int NTW>
__device__ __forceinline__ void loadB0_3(const ush* __restrict__ Wp, int WPL,
                                         int lane, int ntoff,
                                         bh8 nbh[NTW], bh8 nbm[NTW], bh8 nbl[NTW])
{
    #pragma unroll
    for (int nl = 0; nl < NTW; ++nl) {
        const int fo = ((ntoff + nl) * 64 + lane) * 8;
        nbh[nl] = *(const bh8*)(Wp + fo);
        nbm[nl] = *(const bh8*)(Wp + WPL + fo);
        nbl[nl] = *(const bh8*)(Wp + 2 * WPL + fo);
    }
}

// ---------------------------------------------------------------------------
// 2-plane MFMA GEMM, depth-2 B ring. Slot kc&1 is consumed by MFMA cluster
// kc, then reloaded (kc+2) right after the cluster — loads live across the
// next full iteration (~300+ cyc coverage, matching L2-hit latency). kc is
// fully unrolled so kc&1 indexing is static (no scratch).
// A off(row,k) = ((kc*MT+row/16)*4+(k>>3)&3)*128 + rowperm(row&15)*8 + (k&7)
// ---------------------------------------------------------------------------
template<int KC, int NTW, int NT, int MT, int MTW>
__device__ __forceinline__ void gemm2p(const ush* __restrict__ Ah, const ush* __restrict__ Al,
                                       const ush* __restrict__ Wh, const ush* __restrict__ Wl,
                                       int lane, int mtoff, int ntoff, f4 acc[MTW][NTW],
                                       bh8 nbh[NTW], bh8 nbl[NTW])
{
    const int q = lane >> 4, m = lane & 15;
    const int mp8 = rowperm(m) * 8;
    bh8 rbh[2][NTW], rbl[2][NTW];
    #pragma unroll
    for (int nl = 0; nl < NTW; ++nl) { rbh[0][nl] = nbh[nl]; rbl[0][nl] = nbl[nl]; }
    if (KC > 1) {
        #pragma unroll
        for (int nl = 0; nl < NTW; ++nl) {
            const int fo = ((NT + ntoff + nl) * 64 + lane) * 8;
            rbh[1][nl] = *(const bh8*)(Wh + fo);
            rbl[1][nl] = *(const bh8*)(Wl + fo);
        }
    }
    #pragma unroll
    for (int kc = 0; kc < KC; ++kc) {
        bh8 ah[MTW], al[MTW];
        #pragma unroll
        for (int mtw = 0; mtw < MTW; ++mtw) {
            const int off = ((kc * MT + mtoff + mtw) * 4 + q) * 128 + mp8;
            ah[mtw] = *(const bh8*)(Ah + off);
            al[mtw] = *(const bh8*)(Al + off);
        }
        __builtin_amdgcn_sched_barrier(GEMM_FENCE);   // VMEM/MFMA pinned; A free
        #pragma unroll
        for (int nl = 0; nl < NTW; ++nl)
            #pragma unroll
            for (int mtw = 0; mtw < MTW; ++mtw) {
                acc[mtw][nl] = __builtin_amdgcn_mfma_f32_16x16x32_bf16(al[mtw], rbh[kc & 1][nl], acc[mtw][nl], 0, 0, 0);
                acc[mtw][nl] = __builtin_amdgcn_mfma_f32_16x16x32_bf16(ah[mtw], rbl[kc & 1][nl], acc[mtw][nl], 0, 0, 0);
                acc[mtw][nl] = __builtin_amdgcn_mfma_f32_16x16x32_bf16(ah[mtw], rbh[kc & 1][nl], acc[mtw][nl], 0, 0, 0);
            }
        if (kc + 2 < KC) {   // reload consumed slot for kc+2; in flight ~1 iter
            #pragma unroll
            for (int nl = 0; nl < NTW; ++nl) {
                const int fo = (((kc + 2) * NT + ntoff + nl) * 64 + lane) * 8;
                rbh[kc & 1][nl] = *(const bh8*)(Wh + fo);
                rbl[kc & 1][nl] = *(const bh8*)(Wl + fo);
            }
        }
    }
}

// Fused heads GEMM: one pass over A (9 kc) feeding BOTH sigma (8 kc) and
// color (9 kc) accumulators — halves heads A-LDS traffic vs two gemms.
template<int MT, int MTW>
__device__ __forceinline__ void gemm_heads(
    const ush* __restrict__ Ah, const ush* __restrict__ Al,
    const ush* __restrict__ Wsh, const ush* __restrict__ Wsl,
    const ush* __restrict__ Wch, const ush* __restrict__ Wcl,
    int lane, int mtoff, int ntoff, f4 sacc[MTW], f4 cacc[MTW],
    bh8 nsh, bh8 nsl, bh8 nch, bh8 ncl)
{
    const int q = lane >> 4, m = lane & 15;
    const int mp8 = rowperm(m) * 8;
    #pragma unroll
    for (int kc = 0; kc < 9; ++kc) {
        bh8 ah[MTW], al[MTW];
        #pragma unroll
        for (int mtw = 0; mtw < MTW; ++mtw) {
            const int off = ((kc * MT + mtoff + mtw) * 4 + q) * 128 + mp8;
            ah[mtw] = *(const bh8*)(Ah + off);
            al[mtw] = *(const bh8*)(Al + off);
        }
        bh8 sh = nsh, sl = nsl, ch = nch, cl = ncl;
        if (kc + 1 < 8) {
            const int fo = (((kc + 1) * 8 + ntoff) * 64 + lane) * 8;
            nsh = *(const bh8*)(Wsh + fo);
            nsl = *(const bh8*)(Wsl + fo);
        }
        if (kc + 1 < 9) {
            const int fo = (((kc + 1) * 8 + ntoff) * 64 + lane) * 8;
            nch = *(const bh8*)(Wch + fo);
            ncl = *(const bh8*)(Wcl + fo);
        }
        __builtin_amdgcn_sched_barrier(GEMM_FENCE);
        #pragma unroll
        for (int mtw = 0; mtw < MTW; ++mtw) {
            if (kc < 8) {
                sacc[mtw] = __builtin_amdgcn_mfma_f32_16x16x32_bf16(al[mtw], sh, sacc[mtw], 0, 0, 0);
                sacc[mtw] = __builtin_amdgcn_mfma_f32_16x16x32_bf16(ah[mtw], sl, sacc[mtw], 0, 0, 0);
                sacc[mtw] = __builtin_amdgcn_mfma_f32_16x16x32_bf16(ah[mtw], sh, sacc[mtw], 0, 0, 0);
            }
            cacc[mtw] = __builtin_amdgcn_mfma_f32_16x16x32_bf16(al[mtw], ch, cacc[mtw], 0, 0, 0);
            cacc[mtw] = __builtin_amdgcn_mfma_f32_16x16x32_bf16(ah[mtw], cl, cacc[mtw], 0, 0, 0);
            cacc[mtw] = __builtin_amdgcn_mfma_f32_16x16x32_bf16(ah[mtw], ch, cacc[mtw], 0, 0, 0);
        }
    }
}

// 3-plane MFMA GEMM (trunk l1 only, gate-accuracy), caller-preloaded B0.
// Plane stride KC*MT*512; W planes stride KC*8192; NT = 16. KC=2 -> no ring.
template<int KC, int NTW, int MT, int MTW>
__device__ __forceinline__ void gemm3(const ush* __restrict__ Ap, const ush* __restrict__ Wp,
                                      int lane, int mtoff, int ntoff, f4 acc[MTW][NTW],
                                      bh8 nbh[NTW], bh8 nbm[NTW], bh8 nbl[NTW])
{
    const int q = lane >> 4, m = lane & 15;
    const int mp8 = rowperm(m) * 8;
    const int APL = KC * MT * 512;
    const int WPL = KC * 8192;
    #pragma unroll
    for (int kc = 0; kc < KC; ++kc) {
        bh8 ah[MTW], am[MTW], al[MTW];
        #pragma unroll
        for (int mtw = 0; mtw < MTW; ++mtw) {
            const int off = ((kc * MT + mtoff + mtw) * 4 + q) * 128 + mp8;
            ah[mtw] = *(const bh8*)(Ap + off);
            am[mtw] = *(const bh8*)(Ap + APL + off);
            al[mtw] = *(const bh8*)(Ap + 2 * APL + off);
        }
        bh8 bh[NTW], bm[NTW], bl[NTW];
        #pragma unroll
        for (int nl = 0; nl < NTW; ++nl) { bh[nl] = nbh[nl]; bm[nl] = nbm[nl]; bl[nl] = nbl[nl]; }
        if (kc + 1 < KC) {
            #pragma unroll
            for (int nl = 0; nl < NTW; ++nl) {
                const int fo = (((kc + 1) * 16 + ntoff + nl) * 64 + lane) * 8;
                nbh[nl] = *(const bh8*)(Wp + fo);
                nbm[nl] = *(const bh8*)(Wp + WPL + fo);
                nbl[nl] = *(const bh8*)(Wp + 2 * WPL + fo);
            }
        }
        __builtin_amdgcn_sched_barrier(GEMM_FENCE);
        #pragma unroll
        for (int nl = 0; nl < NTW; ++nl)
            #pragma unroll
            for (int mtw = 0; mtw < MTW; ++mtw) {
                acc[mtw][nl] = __builtin_amdgcn_mfma_f32_16x16x32_bf16(ah[mtw], bl[nl], acc[mtw][nl], 0, 0, 0);
                acc[mtw][nl] = __builtin_amdgcn_mfma_f32_16x16x32_bf16(am[mtw], bm[nl], acc[mtw][nl], 0, 0, 0);
                acc[mtw][nl] = __builtin_amdgcn_mfma_f32_16x16x32_bf16(al[mtw], bh[nl], acc[mtw][nl], 0, 0, 0);
                acc[mtw][nl] = __builtin_amdgcn_mfma_f32_16x16x32_bf16(ah[mtw], bm[nl], acc[mtw][nl], 0, 0, 0);
                acc[mtw][nl] = __builtin_amdgcn_mfma_f32_16x16x32_bf16(am[mtw], bh[nl], acc[mtw][nl], 0, 0, 0);
                acc[mtw][nl] = __builtin_amdgcn_mfma_f32_16x16x32_bf16(ah[mtw], bh[nl], acc[mtw][nl], 0, 0, 0);
            }
    }
}

// ---------------------------------------------------------------------------
// Fused weight prep (unchanged).
// ---------------------------------------------------------------------------
__global__ void prep_all(const float* __restrict__ We, ush* __restrict__ EWp,
                         const float* __restrict__ Ws1, ush* __restrict__ Ws1p,
                         const float* __restrict__ Wc1, ush* __restrict__ Wc1p,
                         const float* __restrict__ W1, ush* __restrict__ W1p,
                         const float* __restrict__ W2, ush* __restrict__ W2p2,
                         const float* __restrict__ b2,
                         const float* __restrict__ Wg, const float* __restrict__ bg,
                         float* __restrict__ Wg2, float* __restrict__ bg2,
                         int* __restrict__ counts)
{
    const int blk = blockIdx.x;
    if (blk < 1024) {                       // expert weights, 2-plane
        const int gid = blk * 256 + threadIdx.x;
        const int nn = gid & 15, nt = (gid >> 4) & 15, qd = (gid >> 8) & 3;
        const int kc = (gid >> 10) & 7, el = gid >> 13;
        const int n = nt * 16 + nn;
        const float* src = We + (size_t)el * 65536 + (size_t)(kc * 32 + qd * 8) * 256 + n;
        union { ush u[8]; bh8 v; } H, L;
        #pragma unroll
        for (int j = 0; j < 8; ++j) bfsplit(src[j * 256], H.u[j], L.u[j]);
        ush* d = EWp + (size_t)el * 131072 + (size_t)((kc * 16 + nt) * 64 + qd * 16 + nn) * 8;
        *(bh8*)d = H.v;
        *(bh8*)(d + 65536) = L.v;
    } else if (blk < 1058) {                // head weights, 2-plane
        const int isC = blk >= 1040;
        const int gid = (isC ? blk - 1040 : blk - 1024) * 256 + threadIdx.x;
        const int KC = isC ? 9 : 8, Kreal = isC ? 283 : 256;
        if (gid >= KC * 512) return;
        const float* W = isC ? Wc1 : Ws1;
        ush* dst = isC ? Wc1p : Ws1p;
        const int nn = gid & 15, nt = (gid >> 4) & 7, qd = (gid >> 7) & 3, kc = gid >> 9;
        const int n = nt * 16 + nn;
        union { ush u[8]; bh8 v; } H, L;
        #pragma unroll
        for (int j = 0; j < 8; ++j) {
            const int k = kc * 32 + qd * 8 + j;
            const float x = (k < Kreal) ? W[k * 128 + n] : 0.f;
            bfsplit(x, H.u[j], L.u[j]);
        }
        ush* d = dst + (size_t)((kc * 8 + nt) * 64 + qd * 16 + nn) * 8;
        *(bh8*)d = H.v;
        *(bh8*)(d + KC * 4096) = L.v;
    } else if (blk < 1066) {                // trunk W1, 3-plane
        const int gid = (blk - 1058) * 256 + threadIdx.x;
        const int KC = 2, Kreal = 63;
        const int n15 = gid & 15, qd = (gid >> 4) & 3, nt = (gid >> 6) & 15, kc = gid >> 10;
        const int n = nt * 16 + n15;
        const int plane = KC * 8192;
        union { ush u[8]; bh8 v; } H, M, L;
        #pragma unroll
        for (int j = 0; j < 8; ++j) {
            const int k = kc * 32 + qd * 8 + j;
            const float x = (k < Kreal) ? W1[k * 256 + n] : 0.f;
            bfsplit3(x, H.u[j], M.u[j], L.u[j]);
        }
        ush* d = W1p + (size_t)gid * 8;
        *(bh8*)d = H.v;
        *(bh8*)(d + plane) = M.v;
        *(bh8*)(d + 2 * plane) = L.v;
    } else if (blk < 1098) {                // trunk W2, 2-plane
        const int gid = (blk - 1066) * 256 + threadIdx.x;
        const int KC = 8;
        const int n15 = gid & 15, qd = (gid >> 4) & 3, nt = (gid >> 6) & 15, kc = gid >> 10;
        const int n = nt * 16 + n15;
        const int plane = KC * 8192;
        union { ush u[8]; bh8 v; } H, L;
        #pragma unroll
        for (int j = 0; j < 8; ++j) {
            const int k = kc * 32 + qd * 8 + j;
            bfsplit(W2[k * 256 + n], H.u[j], L.u[j]);
        }
        ush* d = W2p2 + (size_t)gid * 8;
        *(bh8*)d = H.v;
        *(bh8*)(d + plane) = L.v;
    } else if (blk < 1106) {                // fused gate: Wg2 = W2@Wg, bg2
        const int gid = (blk - 1098) * 256 + threadIdx.x;
        const int k = gid >> 3, e = gid & 7;
        float s = 0.f;
        for (int j = 0; j < HD; ++j) s += W2[k * HD + j] * Wg[j * NE + e];
        Wg2[k * NE + e] = s;
        if (gid < NE) {
            float t = bg[gid];
            for (int j = 0; j < HD; ++j) t += b2[j] * Wg[j * NE + gid];
            bg2[gid] = t;
        }
    } else {                                // counts zeroing
        if (threadIdx.x < NE) counts[threadIdx.x] = 0;
    }
}

// ---------------------------------------------------------------------------
// Kernel 1: posenc -> l1 (3-plane 6-term) -> l2 (2-plane 3-term) -> fused gate
// + bucket. 32 rows/block, 512 thr, 2 blocks/CU.
// ---------------------------------------------------------------------------
__global__ void __attribute__((amdgpu_flat_work_group_size(512, 512), amdgpu_waves_per_eu(4, 4)))
trunk_kernel(
    const float* __restrict__ xyz,
    const ush* __restrict__ W1p, const float* __restrict__ b1,
    const ush* __restrict__ W2p2, const float* __restrict__ b2,
    const float* __restrict__ Wg2, const float* __restrict__ bg2,
    unsigned* __restrict__ h2p, float* __restrict__ gateout,
    int* __restrict__ counts, int* __restrict__ bucket)
{
    __shared__ ush   exP[3 * 2048];   // posenc 3 planes (KC=2, MT=2); later gate partials
    __shared__ ush   h1h[8192];       // h1 hi plane (KC=8, MT=2)
    __shared__ ush   h1l[8192];       // h1 lo plane
    __shared__ float h1f[32 * 259];   // h1 fp32 (gate path)
    __shared__ int   lcount[NE], lbase[NE], lpos[32], lexp[32];

    const int tid  = threadIdx.x;
    const int row0 = blockIdx.x * 32;
    const int lane = tid & 63, wv = tid >> 6;
    const int q = lane >> 4, n15 = lane & 15;
    if (tid < NE) lcount[tid] = 0;

    {   // posenc: thread (row, g) writes 4 k's
        const int row = tid & 31, g = tid >> 5;
        const int i = row0 + row;
        const float xv[3] = {xyz[3 * i], xyz[3 * i + 1], xyz[3 * i + 2]};
        const int mt = row >> 4, m = row & 15;
        const int mp8 = rowperm(m) * 8;
        #pragma unroll
        for (int kk = 0; kk < 4; ++kk) {
            const int k = g * 4 + kk;
            float v = 0.f;
            if (k < 3) v = xv[k];
            else if (k < 63) {
                const int l = (k - 3) / 6, c = (k - 3) % 6;
                const float f = (float)(1 << l);
                v = (c < 3) ? sinf(f * xv[c]) : cosf(f * xv[c - 3]);
            }
            const int kc = k >> 5, qq = (k >> 3) & 3, j = k & 7;
            const int off = ((kc * 2 + mt) * 4 + qq) * 128 + mp8 + j;
            ush hh, mm, ll; split3t(v, hh, mm, ll);
            exP[off] = hh; exP[2048 + off] = mm; exP[4096 + off] = ll;
        }
    }
    // l1's kc=0 B (3 planes) prefetch: issued after posenc, rides the barrier
    bh8 p3h[2], p3m[2], p3l[2];
    loadB0_3<2>(W1p, 2 * 8192, lane, wv * 2, p3h, p3m, p3l);
    lds_barrier();

    bh8 pbh[2], pbl[2];   // l2's B0 ring

    // --- l1 = relu(ex @ W1 + b1): 6-term; store fp32 (gate) + 2-plane (l2) ---
    {
        f4 acc[2][2];
        #pragma unroll
        for (int a = 0; a < 2; ++a)
            #pragma unroll
            for (int b_ = 0; b_ < 2; ++b_) acc[a][b_] = (f4){0.f, 0.f, 0.f, 0.f};
        gemm3<2, 2, 2, 2>(exP, W1p, lane, 0, wv * 2, acc, p3h, p3m, p3l);
        loadB0<2>(W2p2, W2p2 + 65536, lane, wv * 2, pbh, pbl);   // l2 B0 in flight
        #pragma unroll
        for (int nl = 0; nl < 2; ++nl) {
            const int col = wv * 32 + nl * 16 + n15;
            const float bias = b1[col];
            const int kc = col >> 5, qc = (col >> 3) & 3, jc = col & 7;
            #pragma unroll
            for (int mt = 0; mt < 2; ++mt)
                #pragma unroll
                for (int r = 0; r < 4; ++r) {
                    const int row = mt * 16 + q * 4 + r;
                    const float v = fmaxf(acc[mt][nl][r] + bias, 0.f);
                    const int off = ((kc * 2 + mt) * 4 + qc) * 128 + (q * 4 + (r ^ q)) * 8 + jc;
                    ush hh, ll; split2t(v, hh, ll);
                    h1h[off] = hh; h1l[off] = ll;
                    h1f[row * 259 + col] = v;
                }
        }
    }
    lds_barrier();

    // --- l2 = h1 @ W2 + b2: 2-plane 3-term; epilogue straight to global ---
    {
        f4 acc[2][2];
        #pragma unroll
        for (int a = 0; a < 2; ++a)
            #pragma unroll
            for (int b_ = 0; b_ < 2; ++b_) acc[a][b_] = (f4){0.f, 0.f, 0.f, 0.f};
        gemm2p<8, 2, 16, 2, 2>(h1h, h1l, W2p2, W2p2 + 65536, lane, 0, wv * 2, acc, pbh, pbl);
        lds_barrier();   // all h1h/h1l reads done before part overlay
        #pragma unroll
        for (int nl = 0; nl < 2; ++nl) {
            const int col = wv * 32 + nl * 16 + n15;
            const float bias = b2[col];
            #pragma unroll
            for (int mt = 0; mt < 2; ++mt)
                #pragma unroll
                for (int r = 0; r < 4; ++r) {
                    const int row = mt * 16 + q * 4 + r;
                    h2p[(size_t)(row0 + row) * HD + col] = pack2t(acc[mt][nl][r] + bias);
                }
        }
    }

    // --- gate partials from h1f via fused Wg2 (h1f stable; exP dead) ---
    float* part = (float*)exP;        // [8][32][8]
    if (tid < 256) {
        const int row = tid & 31, seg = tid >> 5, k0 = seg * 32;
        float lg[NE];
        #pragma unroll
        for (int e = 0; e < NE; ++e) lg[e] = 0.f;
        for (int k = k0; k < k0 + 32; ++k) {
            const float hv = h1f[row * 259 + k];
            const float4 w0 = *(const float4*)(Wg2 + k * 8);
            const float4 w1 = *(const float4*)(Wg2 + k * 8 + 4);
            lg[0] = fmaf(hv, w0.x, lg[0]); lg[1] = fmaf(hv, w0.y, lg[1]);
            lg[2] = fmaf(hv, w0.z, lg[2]); lg[3] = fmaf(hv, w0.w, lg[3]);
            lg[4] = fmaf(hv, w1.x, lg[4]); lg[5] = fmaf(hv, w1.y, lg[5]);
            lg[6] = fmaf(hv, w1.z, lg[6]); lg[7] = fmaf(hv, w1.w, lg[7]);
        }
        #pragma unroll
        for (int e = 0; e < NE; ++e) part[(seg * 32 + row) * 8 + e] = lg[e];
    }
    lds_barrier();

    if (tid < 32) {
        float lg[NE];
        #pragma unroll
        for (int e = 0; e < NE; ++e) {
            float s = bg2[e];
            #pragma unroll
            for (int sg = 0; sg < 8; ++sg) s += part[(sg * 32 + tid) * 8 + e];
            lg[e] = s;
        }
        int best = 0; float mx = lg[0];
        #pragma unroll
        for (int e = 1; e < NE; ++e) if (lg[e] > mx) { mx = lg[e]; best = e; }
        float s = 0.f;
        #pragma unroll
        for (int e = 0; e < NE; ++e) s += expf(lg[e] - mx);
        gateout[row0 + tid] = 1.f / s;
        lexp[tid] = best;
        lpos[tid] = atomicAdd(&lcount[best], 1);
    }
    lds_barrier();
    if (tid < NE) lbase[tid] = atomicAdd(&counts[tid], lcount[tid]);
    lds_barrier();
    if (tid < 32) {
        const int e = lexp[tid];
        bucket[e * NS + lbase[e] + lpos[tid]] = row0 + tid;
    }
}

// ---------------------------------------------------------------------------
// Kernel 2: expert MLP + heads. 64 rows, 8 waves all-M MT=4, NTW=2; LDS 78KB
// -> 2 blocks/CU. e = blockIdx&7: blocks dispatch round-robin across the 8
// XCDs, so each expert's 2MB weight set pins to one XCD's 4MB L2 (B-load
// latency ~600 (L3) -> ~200 (L2)). Depth-2 B ring covers the remaining ~200.
// ---------------------------------------------------------------------------
__global__ void __attribute__((amdgpu_flat_work_group_size(512, 512), amdgpu_waves_per_eu(4, 4)))
expert_kernel(
    const unsigned* __restrict__ h2p, const float* __restrict__ gatebuf,
    const int* __restrict__ counts, const int* __restrict__ bucket,
    const ush* __restrict__ EWp, const float* __restrict__ be,
    const float* __restrict__ dirs,
    const ush* __restrict__ Ws1p, const float* __restrict__ bs1,
    const float* __restrict__ Ws2, const float* __restrict__ bs2,
    const ush* __restrict__ Wc1p, const float* __restrict__ bc1,
    const float* __restrict__ Wc2, const float* __restrict__ bc2,
    float* __restrict__ outp)
{
    __shared__ ush   Ah[9 * 2048];      // hi plane (KC=9 incl. dirs ext); later fp32 s
    __shared__ ush   Al[9 * 2048];      // lo plane;                       later fp32 c
    __shared__ float dotp[4 * 64 * 4];
    __shared__ int   idx[64];
    __shared__ float gatev[64];

    const int tid = threadIdx.x;
    const int e   = blockIdx.x & 7;       // XCD-pin: expert e -> XCD e
    const int t   = blockIdx.x >> 3;
    const int cnt = counts[e];
    if (t * 64 >= cnt) return;
    const int nact = min(64, cnt - t * 64);

    const int lane = tid & 63, wv = tid >> 6;
    const int q = lane >> 4, n15 = lane & 15;

    const float* bb = be + e * 4 * HD;
    const ush* W0 = EWp + (size_t)(e * 4) * 131072;

    // l0 B0 prefetch: in flight across idx load + gather + barrier
    bh8 pbh[2], pbl[2];
    loadB0<2>(W0, W0 + 65536, lane, wv * 2, pbh, pbl);

    if (tid < 64) {
        const int src = bucket[e * NS + t * 64 + min(tid, nact - 1)];
        idx[tid]   = src;
        gatev[tid] = gatebuf[src];
    }
    lds_barrier();

    {   // gather: wave wv -> kc=wv, lane = row; unpack packed h2 into planes
        const int row = lane, mt = row >> 4, m = row & 15;
        const int mp8 = rowperm(m) * 8;
        const unsigned* src = h2p + (size_t)idx[row] * HD + wv * 32;
        #pragma unroll
        for (int sub = 0; sub < 4; ++sub) {
            bh8 hv, lv;
            unpack8(src + sub * 8, hv, lv);
            const int off = ((wv * 4 + mt) * 4 + sub) * 128 + mp8;
            *(bh8*)(Ah + off) = hv;
            *(bh8*)(Al + off) = lv;
        }
    }
    if (tid < 64) {   // dirs posenc ext -> kc=8 region
        const int row = tid, i = idx[row];
        const int mt = row >> 4, m = row & 15;
        const int mp8 = rowperm(m) * 8;
        const float d0 = dirs[3 * i], d1 = dirs[3 * i + 1], d2 = dirs[3 * i + 2];
        float vals[32];
        vals[0] = d0; vals[1] = d1; vals[2] = d2;
        float f = 1.f;
        #pragma unroll
        for (int l = 0; l < 4; ++l) {
            vals[3 + 6 * l + 0] = sinf(f * d0);
            vals[3 + 6 * l + 1] = sinf(f * d1);
            vals[3 + 6 * l + 2] = sinf(f * d2);
            vals[3 + 6 * l + 3] = cosf(f * d0);
            vals[3 + 6 * l + 4] = cosf(f * d1);
            vals[3 + 6 * l + 5] = cosf(f * d2);
            f *= 2.f;
        }
        #pragma unroll
        for (int c = 27; c < 32; ++c) vals[c] = 0.f;
        #pragma unroll
        for (int k2 = 0; k2 < 32; ++k2) {
            const int off = ((8 * 4 + mt) * 4 + (k2 >> 3)) * 128 + mp8 + (k2 & 7);
            ush hh, ll; split2t(vals[k2], hh, ll);
            Ah[off] = hh; Al[off] = ll;
        }
    }
    lds_barrier();

    // ---- l0: A <- relu(A @ W0 + b0); capture skip (old A) into l1's acc ----
    f4 acc1[4][2];   // l1 accumulator, seeded with the skip values
    {
        f4 acc[4][2];
        #pragma unroll
        for (int mt = 0; mt < 4; ++mt)
            #pragma unroll
            for (int nl = 0; nl < 2; ++nl) acc[mt][nl] = (f4){0.f, 0.f, 0.f, 0.f};
        gemm2p<8, 2, 16, 4, 4>(Ah, Al, W0, W0 + 65536, lane, 0, wv * 2, acc, pbh, pbl);
        loadB0<2>(W0 + 131072, W0 + 131072 + 65536, lane, wv * 2, pbh, pbl);   // l1 B0
        lds_barrier();
        #pragma unroll
        for (int nl = 0; nl < 2; ++nl) {
            const int col = wv * 32 + nl * 16 + n15;
            const float bias = bb[col];
            const int kc = col >> 5, qc = (col >> 3) & 3, jc = col & 7;
            #pragma unroll
            for (int mt = 0; mt < 4; ++mt)
                #pragma unroll
                for (int r = 0; r < 4; ++r) {
                    const int off = ((kc * 4 + mt) * 4 + qc) * 128 + (q * 4 + (r ^ q)) * 8 + jc;
                    // capture old value (= h2[row][col], the l1 skip) before overwrite
                    acc1[mt][nl][r] = planes2f(Ah[off], Al[off]);
                    const float v = fmaxf(acc[mt][nl][r] + bias, 0.f);
                    ush hh, ll; split2t(v, hh, ll);
                    Ah[off] = hh; Al[off] = ll;
                }
        }
        lds_barrier();
    }
    // ---- l1: A <- relu(A @ W1 + b1 + skip); skip pre-seeded in acc1 ----
    {
        gemm2p<8, 2, 16, 4, 4>(Ah, Al, W0 + 131072, W0 + 131072 + 65536, lane, 0, wv * 2, acc1, pbh, pbl);
        loadB0<2>(W0 + 2 * 131072, W0 + 2 * 131072 + 65536, lane, wv * 2, pbh, pbl);   // l2 B0
        lds_barrier();
        #pragma unroll
        for (int nl = 0; nl < 2; ++nl) {
            const int col = wv * 32 + nl * 16 + n15;
            const float bias = bb[256 + col];
            const int kc = col >> 5, qc = (col >> 3) & 3, jc = col & 7;
            #pragma unroll
            for (int mt = 0; mt < 4; ++mt)
                #pragma unroll
                for (int r = 0; r < 4; ++r) {
                    const int off = ((kc * 4 + mt) * 4 + qc) * 128 + (q * 4 + (r ^ q)) * 8 + jc;
                    const float v = fmaxf(acc1[mt][nl][r] + bias, 0.f);
                    ush hh, ll; split2t(v, hh, ll);
                    Ah[off] = hh; Al[off] = ll;
                }
        }
        lds_barrier();
    }
    // ---- l2: A <- relu(A @ W2 + b2) ----
    {
        f4 acc[4][2];
        #pragma unroll
        for (int mt = 0; mt < 4; ++mt)
            #pragma unroll
            for (int nl = 0; nl < 2; ++nl) acc[mt][nl] = (f4){0.f, 0.f, 0.f, 0.f};
        gemm2p<8, 2, 16, 4, 4>(Ah, Al, W0 + 2 * 131072, W0 + 2 * 131072 + 65536, lane, 0, wv * 2, acc, pbh, pbl);
        loadB0<2>(W0 + 3 * 131072, W0 + 3 * 131072 + 65536, lane, wv * 2, pbh, pbl);   // l3 B0
        lds_barrier();
        #pragma unroll
        for (int nl = 0; nl < 2; ++nl) {
            const int col = wv * 32 + nl * 16 + n15;
            const float bias = bb[512 + col];
            const int kc = col >> 5, qc = (col >> 3) & 3, jc = col & 7;
            #pragma unroll
            for (int mt = 0; mt < 4; ++mt)
                #pragma unroll
                for (int r = 0; r < 4; ++r) {
                    const int off = ((kc * 4 + mt) * 4 + qc) * 128 + (q * 4 + (r ^ q)) * 8 + jc;
                    const float v = fmaxf(acc[mt][nl][r] + bias, 0.f);
                    ush hh, ll; split2t(v, hh, ll);
                    Ah[off] = hh; Al[off] = ll;
                }
        }
        lds_barrier();
    }
    // ---- l3: A <- gate * (A @ W3 + b3)  (no relu) ----
    bh8 sb0h, sb0l, cb0h, cb0l;   // heads kc=0 B prefetch
    {
        f4 acc[4][2];
        #pragma unroll
        for (int mt = 0; mt < 4; ++mt)
            #pragma unroll
            for (int nl = 0; nl < 2; ++nl) acc[mt][nl] = (f4){0.f, 0.f, 0.f, 0.f};
        gemm2p<8, 2, 16, 4, 4>(Ah, Al, W0 + 3 * 131072, W0 + 3 * 131072 + 65536, lane, 0, wv * 2, acc, pbh, pbl);
        {
            const int fo = (wv * 64 + lane) * 8;
            sb0h = *(const bh8*)(Ws1p + fo);
            sb0l = *(const bh8*)(Ws1p + 32768 + fo);
            cb0h = *(const bh8*)(Wc1p + fo);
            cb0l = *(const bh8*)(Wc1p + 36864 + fo);
        }
        lds_barrier();
        #pragma unroll
        for (int nl = 0; nl < 2; ++nl) {
            const int col = wv * 32 + nl * 16 + n15;
            const float bias = bb[768 + col];
            const int kc = col >> 5, qc = (col >> 3) & 3, jc = col & 7;
            #pragma unroll
            for (int mt = 0; mt < 4; ++mt)
                #pragma unroll
                for (int r = 0; r < 4; ++r) {
                    const int row = mt * 16 + q * 4 + r;
                    const int off = ((kc * 4 + mt) * 4 + qc) * 128 + (q * 4 + (r ^ q)) * 8 + jc;
                    const float v = gatev[row] * (acc[mt][nl][r] + bias);
                    ush hh, ll; split2t(v, hh, ll);
                    Ah[off] = hh; Al[off] = ll;
                }
        }
        lds_barrier();
    }

    // ---- heads (fused): s = relu(out@Ws1+bs1), c = relu([out,ed]@Wc1+bc1) ----
    {
        f4 sacc[4], cacc[4];
        #pragma unroll
        for (int mt = 0; mt < 4; ++mt) {
            sacc[mt] = (f4){0.f, 0.f, 0.f, 0.f};
            cacc[mt] = (f4){0.f, 0.f, 0.f, 0.f};
        }
        gemm_heads<4, 4>(Ah, Al, Ws1p, Ws1p + 32768, Wc1p, Wc1p + 36864,
                         lane, 0, wv, sacc, cacc, sb0h, sb0l, cb0h, cb0l);
        lds_barrier();
        float* sp = (float*)Ah;          // [64][133]
        float* cp = (float*)Al;
        const int col = wv * 16 + n15;
        const float b_s = bs1[col], b_c = bc1[col];
        #pragma unroll
        for (int mt = 0; mt < 4; ++mt)
            #pragma unroll
            for (int r = 0; r < 4; ++r) {
                const int row = mt * 16 + q * 4 + r;
                sp[row * 133 + col] = fmaxf(sacc[mt][r] + b_s, 0.f);
                cp[row * 133 + col] = fmaxf(cacc[mt][r] + b_c, 0.f);
            }
        lds_barrier();
    }
    // ---- final dots: 4 segs x 64 rows, 32 k each ----
    if (tid < 256) {
        const float* sp = (const float*)Ah;
        const float* cp = (const float*)Al;
        const int row = tid & 63, seg = tid >> 6, k0 = seg * 32;
        float ps = 0.f, p0 = 0.f, p1 = 0.f, p2 = 0.f;
        for (int k = k0; k < k0 + 32; ++k) {
            ps = fmaf(sp[row * 133 + k], Ws2[k], ps);
            const float cv = cp[row * 133 + k];
            p0 = fmaf(cv, Wc2[3 * k + 0], p0);
            p1 = fmaf(cv, Wc2[3 * k + 1], p1);
            p2 = fmaf(cv, Wc2[3 * k + 2], p2);
        }
        *(float4*)&dotp[(seg * 64 + row) * 4] = make_float4(ps, p0, p1, p2);
    }
    lds_barrier();
    if (tid < nact) {
        float sg = bs2[0], r0 = bc2[0], r1 = bc2[1], r2 = bc2[2];
        #pragma unroll
        for (int s2 = 0; s2 < 4; ++s2) {
            const float4 pv = *(const float4*)&dotp[(s2 * 64 + tid) * 4];
            sg += pv.x; r0 += pv.y; r1 += pv.z; r2 += pv.w;
        }
        float4 o;
        o.x = 1.f / (1.f + expf(-r0));
        o.y = 1.f / (1.f + expf(-r1));
        o.z = 1.f / (1.f + expf(-r2));
        o.w = fmaxf(sg, 0.f) + log1pf(expf(-fabsf(sg)));
        *(float4*)&outp[(size_t)idx[tid] * 4] = o;
    }
}

// ---------------------------------------------------------------------------
extern "C" void kernel_launch(void* const* d_in, const int* in_sizes, int n_in,
                              void* d_out, int out_size, void* d_ws, size_t ws_size,
                              hipStream_t stream)
{
    const float* xyz  = (const float*)d_in[0];
    const float* dirs = (const float*)d_in[1];
    const float* W1   = (const float*)d_in[2];
    const float* b1   = (const float*)d_in[3];
    const float* W2   = (const float*)d_in[4];
    const float* b2   = (const float*)d_in[5];
    const float* Wg   = (const float*)d_in[6];
    const float* bg   = (const float*)d_in[7];
    const float* We   = (const float*)d_in[8];
    const float* be   = (const float*)d_in[9];
    const float* Ws1  = (const float*)d_in[10];
    const float* bs1  = (const float*)d_in[11];
    const float* Ws2  = (const float*)d_in[12];
    const float* bs2  = (const float*)d_in[13];
    const float* Wc1  = (const float*)d_in[14];
    const float* bc1  = (const float*)d_in[15];
    const float* Wc2  = (const float*)d_in[16];
    const float* bc2  = (const float*)d_in[17];
    float* out = (float*)d_out;

    char* ws = (char*)d_ws;
    unsigned* h2p     = (unsigned*)ws;                        // 64 MB packed h2
    float*    gatebuf = (float*)(ws + 67108864);              // 256 KB
    int*      counts  = (int*)(ws + 67371008);                // 1 KB (padded)
    int*      bucket  = (int*)(ws + 67372032);                // 2 MB
    ush*      EWp     = (ush*)(ws + 69469184);                // 8 MB expert frags
    ush*      Ws1p    = (ush*)(ws + 77857792);                // 128 KB
    ush*      Wc1p    = (ush*)(ws + 77988864);                // 144 KB
    ush*      W1p     = (ush*)(ws + 78136320);                // 96 KB  (3 planes)
    ush*      W2p2    = (ush*)(ws + 78234624);                // 256 KB (2 planes)
    float*    Wg2     = (float*)(ws + 78496768);              // 8 KB
    float*    bg2     = (float*)(ws + 78504960);              // 32 B

    prep_all<<<1107, 256, 0, stream>>>(We, EWp, Ws1, Ws1p, Wc1, Wc1p,
                                       W1, W1p, W2, W2p2, b2, Wg, bg,
                                       Wg2, bg2, counts);
    trunk_kernel<<<NS / 32, 512, 0, stream>>>(xyz, W1p, b1, W2p2, b2, Wg2, bg2,
                                              h2p, gatebuf, counts, bucket);
    expert_kernel<<<NE * 1024, 512, 0, stream>>>(h2p, gatebuf, counts, bucket,
                                                 EWp, be, dirs, Ws1p, bs1, Ws2, bs2,
                                                 Wc1p, bc1, Wc2, bc2, out);
}

// Round 8
// 292.194 us; speedup vs baseline: 1.5931x; 1.5931x over previous
//
#include <hip/hip_runtime.h>
#include <math.h>

#define NS 65536
#define HD 256
#define NE 8

typedef short bh8 __attribute__((ext_vector_type(8)));   // 8 bf16 (A/B frag)
typedef float f4  __attribute__((ext_vector_type(4)));   // MFMA acc
typedef unsigned short ush;

// Row permutation for A-plane LDS layout: m' = m ^ (m>>2) (involution).
__device__ __forceinline__ int rowperm(int m) { return m ^ (m >> 2); }

// Scheduler fence mask: DS_READ(0x100)|VALU(0x2) may cross; VMEM and MFMA may
// not. Pins B-loads/MFMA ordering while letting A-reads software-pipeline.
#define GEMM_FENCE 0x102

// ---------------------------------------------------------------------------
// LDS-only barrier: __syncthreads() drains vmcnt(0) (compiler-emitted), which
// kills cross-barrier global-load pipelining. Every barrier in these kernels
// guards LDS only, so lgkmcnt(0)+s_barrier is sufficient.
// ---------------------------------------------------------------------------
__device__ __forceinline__ void lds_barrier() {
    asm volatile("s_waitcnt lgkmcnt(0)" ::: "memory");
    __builtin_amdgcn_s_barrier();
    __builtin_amdgcn_sched_barrier(0);
}

// ---------------------------------------------------------------------------
// split helpers. Truncate-hi + RHU-lo: err <= 2^-17|x| (2-way), 2^-25 (3-way).
// ---------------------------------------------------------------------------
__device__ __forceinline__ void split2t(float x, ush& h, ush& l) {
    unsigned u = __float_as_uint(x);
    h = (ush)(u >> 16);
    float lo = x - __uint_as_float(u & 0xffff0000u);
    l = (ush)((__float_as_uint(lo) + 0x8000u) >> 16);
}
__device__ __forceinline__ unsigned pack2t(float x) {     // hi | lo<<16
    ush h, l; split2t(x, h, l);
    return (unsigned)h | ((unsigned)l << 16);
}
__device__ __forceinline__ float unpackf(unsigned p) {    // inverse of pack2t
    return __uint_as_float(p << 16) + __uint_as_float(p & 0xffff0000u);
}
// reconstruct from separate hi/lo plane halves
__device__ __forceinline__ float planes2f(ush h, ush l) {
    return __uint_as_float((unsigned)h << 16) + __uint_as_float((unsigned)l << 16);
}
__device__ __forceinline__ void split3t(float x, ush& h, ush& m, ush& l) {
    unsigned u = __float_as_uint(x);
    h = (ush)(u >> 16);
    float r1 = x - __uint_as_float(u & 0xffff0000u);
    unsigned u1 = __float_as_uint(r1);
    m = (ush)(u1 >> 16);
    float r2 = r1 - __uint_as_float(u1 & 0xffff0000u);
    l = (ush)((__float_as_uint(r2) + 0x8000u) >> 16);
}
// RNE splits for one-time weight preps
__device__ __forceinline__ void bfsplit(float x, ush& h, ush& l) {
    unsigned u  = __float_as_uint(x);
    unsigned hb = (u + 0x7fffu + ((u >> 16) & 1u)) & 0xffff0000u;
    h = (ush)(hb >> 16);
    float    lo = x - __uint_as_float(hb);
    unsigned ul = __float_as_uint(lo);
    l = (ush)((ul + 0x7fffu + ((ul >> 16) & 1u)) >> 16);
}
__device__ __forceinline__ void bfsplit3(float x, ush& h, ush& m, ush& l) {
    unsigned u  = __float_as_uint(x);
    unsigned hb = (u + 0x7fffu + ((u >> 16) & 1u)) & 0xffff0000u;
    h = (ush)(hb >> 16);
    float r1 = x - __uint_as_float(hb);
    unsigned u1 = __float_as_uint(r1);
    unsigned mb = (u1 + 0x7fffu + ((u1 >> 16) & 1u)) & 0xffff0000u;
    m = (ush)(mb >> 16);
    float r2 = r1 - __uint_as_float(mb);
    unsigned u2 = __float_as_uint(r2);
    l = (ush)((u2 + 0x7fffu + ((u2 >> 16) & 1u)) >> 16);
}

// 8 packed uint32 -> hi/lo bh8 planes (used once at expert gather)
__device__ __forceinline__ void unpack8(const unsigned* p, bh8& h, bh8& l) {
    uint4 a = *(const uint4*)p;
    uint4 b = *(const uint4*)(p + 4);
    union { unsigned u[4]; bh8 v; } H, L;
    H.u[0] = __builtin_amdgcn_perm(a.y, a.x, 0x05040100u);
    H.u[1] = __builtin_amdgcn_perm(a.w, a.z, 0x05040100u);
    H.u[2] = __builtin_amdgcn_perm(b.y, b.x, 0x05040100u);
    H.u[3] = __builtin_amdgcn_perm(b.w, b.z, 0x05040100u);
    L.u[0] = __builtin_amdgcn_perm(a.y, a.x, 0x07060302u);
    L.u[1] = __builtin_amdgcn_perm(a.w, a.z, 0x07060302u);
    L.u[2] = __builtin_amdgcn_perm(b.y, b.x, 0x07060302u);
    L.u[3] = __builtin_amdgcn_perm(b.w, b.z, 0x07060302u);
    h = H.v; l = L.v;
}

// B0 prefetch helpers: issue kc=0 B fragments early so they fly across
// epilogue + lgkmcnt-only barriers.
template<int NTW>
__device__ __forceinline__ void loadB0(const ush* __restrict__ Wh, const ush* __restrict__ Wl,
                                       int lane, int ntoff, bh8 nbh[NTW], bh8 nbl[NTW])
{
    #pragma unroll
    for (int nl = 0; nl < NTW; ++nl) {
        const int fo = ((ntoff + nl) * 64 + lane) * 8;
        nbh[nl] = *(const bh8*)(Wh + fo);
        nbl[nl] = *(const bh8*)(Wl + fo);
    }
}
template<int NTW>
__device__ __forceinline__ void loadB0_3(const ush* __restrict__ Wp, int WPL,
                                         int lane, int ntoff,
                                         bh8 nbh[NTW], bh8 nbm[NTW], bh8 nbl[NTW])
{
    #pragma unroll
    for (int nl = 0; nl < NTW; ++nl) {
        const int fo = ((ntoff + nl) * 64 + lane) * 8;
        nbh[nl] = *(const bh8*)(Wp + fo);
        nbm[nl] = *(const bh8*)(Wp + WPL + fo);
        nbl[nl] = *(const bh8*)(Wp + 2 * WPL + fo);
    }
}

// ---------------------------------------------------------------------------
// 2-plane MFMA GEMM, depth-2 B ring. Slot kc&1 is consumed by MFMA cluster
// kc, then reloaded (kc+2) right after the cluster — loads live across the
// next full iteration. kc fully unrolled so kc&1 indexing is static.
// A off(row,k) = ((kc*MT+row/16)*4+(k>>3)&3)*128 + rowperm(row&15)*8 + (k&7)
// ---------------------------------------------------------------------------
template<int KC, int NTW, int NT, int MT, int MTW>
__device__ __forceinline__ void gemm2p(const ush* __restrict__ Ah, const ush* __restrict__ Al,
                                       const ush* __restrict__ Wh, const ush* __restrict__ Wl,
                                       int lane, int mtoff, int ntoff, f4 acc[MTW][NTW],
                                       bh8 nbh[NTW], bh8 nbl[NTW])
{
    const int q = lane >> 4, m = lane & 15;
    const int mp8 = rowperm(m) * 8;
    bh8 rbh[2][NTW], rbl[2][NTW];
    #pragma unroll
    for (int nl = 0; nl < NTW; ++nl) { rbh[0][nl] = nbh[nl]; rbl[0][nl] = nbl[nl]; }
    if (KC > 1) {
        #pragma unroll
        for (int nl = 0; nl < NTW; ++nl) {
            const int fo = ((NT + ntoff + nl) * 64 + lane) * 8;
            rbh[1][nl] = *(const bh8*)(Wh + fo);
            rbl[1][nl] = *(const bh8*)(Wl + fo);
        }
    }
    #pragma unroll
    for (int kc = 0; kc < KC; ++kc) {
        bh8 ah[MTW], al[MTW];
        #pragma unroll
        for (int mtw = 0; mtw < MTW; ++mtw) {
            const int off = ((kc * MT + mtoff + mtw) * 4 + q) * 128 + mp8;
            ah[mtw] = *(const bh8*)(Ah + off);
            al[mtw] = *(const bh8*)(Al + off);
        }
        __builtin_amdgcn_sched_barrier(GEMM_FENCE);   // VMEM/MFMA pinned; A free
        #pragma unroll
        for (int nl = 0; nl < NTW; ++nl)
            #pragma unroll
            for (int mtw = 0; mtw < MTW; ++mtw) {
                acc[mtw][nl] = __builtin_amdgcn_mfma_f32_16x16x32_bf16(al[mtw], rbh[kc & 1][nl], acc[mtw][nl], 0, 0, 0);
                acc[mtw][nl] = __builtin_amdgcn_mfma_f32_16x16x32_bf16(ah[mtw], rbl[kc & 1][nl], acc[mtw][nl], 0, 0, 0);
                acc[mtw][nl] = __builtin_amdgcn_mfma_f32_16x16x32_bf16(ah[mtw], rbh[kc & 1][nl], acc[mtw][nl], 0, 0, 0);
            }
        if (kc + 2 < KC) {   // reload consumed slot for kc+2; in flight ~1 iter
            #pragma unroll
            for (int nl = 0; nl < NTW; ++nl) {
                const int fo = (((kc + 2) * NT + ntoff + nl) * 64 + lane) * 8;
                rbh[kc & 1][nl] = *(const bh8*)(Wh + fo);
                rbl[kc & 1][nl] = *(const bh8*)(Wl + fo);
            }
        }
    }
}

// Fused heads GEMM: one pass over A (9 kc) feeding BOTH sigma (8 kc) and
// color (9 kc) accumulators — halves heads A-LDS traffic vs two gemms.
template<int MT, int MTW>
__device__ __forceinline__ void gemm_heads(
    const ush* __restrict__ Ah, const ush* __restrict__ Al,
    const ush* __restrict__ Wsh, const ush* __restrict__ Wsl,
    const ush* __restrict__ Wch, const ush* __restrict__ Wcl,
    int lane, int mtoff, int ntoff, f4 sacc[MTW], f4 cacc[MTW],
    bh8 nsh, bh8 nsl, bh8 nch, bh8 ncl)
{
    const int q = lane >> 4, m = lane & 15;
    const int mp8 = rowperm(m) * 8;
    #pragma unroll
    for (int kc = 0; kc < 9; ++kc) {
        bh8 ah[MTW], al[MTW];
        #pragma unroll
        for (int mtw = 0; mtw < MTW; ++mtw) {
            const int off = ((kc * MT + mtoff + mtw) * 4 + q) * 128 + mp8;
            ah[mtw] = *(const bh8*)(Ah + off);
            al[mtw] = *(const bh8*)(Al + off);
        }
        bh8 sh = nsh, sl = nsl, ch = nch, cl = ncl;
        if (kc + 1 < 8) {
            const int fo = (((kc + 1) * 8 + ntoff) * 64 + lane) * 8;
            nsh = *(const bh8*)(Wsh + fo);
            nsl = *(const bh8*)(Wsl + fo);
        }
        if (kc + 1 < 9) {
            const int fo = (((kc + 1) * 8 + ntoff) * 64 + lane) * 8;
            nch = *(const bh8*)(Wch + fo);
            ncl = *(const bh8*)(Wcl + fo);
        }
        __builtin_amdgcn_sched_barrier(GEMM_FENCE);
        #pragma unroll
        for (int mtw = 0; mtw < MTW; ++mtw) {
            if (kc < 8) {
                sacc[mtw] = __builtin_amdgcn_mfma_f32_16x16x32_bf16(al[mtw], sh, sacc[mtw], 0, 0, 0);
                sacc[mtw] = __builtin_amdgcn_mfma_f32_16x16x32_bf16(ah[mtw], sl, sacc[mtw], 0, 0, 0);
                sacc[mtw] = __builtin_amdgcn_mfma_f32_16x16x32_bf16(ah[mtw], sh, sacc[mtw], 0, 0, 0);
            }
            cacc[mtw] = __builtin_amdgcn_mfma_f32_16x16x32_bf16(al[mtw], ch, cacc[mtw], 0, 0, 0);
            cacc[mtw] = __builtin_amdgcn_mfma_f32_16x16x32_bf16(ah[mtw], cl, cacc[mtw], 0, 0, 0);
            cacc[mtw] = __builtin_amdgcn_mfma_f32_16x16x32_bf16(ah[mtw], ch, cacc[mtw], 0, 0, 0);
        }
    }
}

// 3-plane MFMA GEMM (trunk l1 only, gate-accuracy), caller-preloaded B0.
// Plane stride KC*MT*512; W planes stride KC*8192; NT = 16. KC=2 -> no ring.
template<int KC, int NTW, int MT, int MTW>
__device__ __forceinline__ void gemm3(const ush* __restrict__ Ap, const ush* __restrict__ Wp,
                                      int lane, int mtoff, int ntoff, f4 acc[MTW][NTW],
                                      bh8 nbh[NTW], bh8 nbm[NTW], bh8 nbl[NTW])
{
    const int q = lane >> 4, m = lane & 15;
    const int mp8 = rowperm(m) * 8;
    const int APL = KC * MT * 512;
    const int WPL = KC * 8192;
    #pragma unroll
    for (int kc = 0; kc < KC; ++kc) {
        bh8 ah[MTW], am[MTW], al[MTW];
        #pragma unroll
        for (int mtw = 0; mtw < MTW; ++mtw) {
            const int off = ((kc * MT + mtoff + mtw) * 4 + q) * 128 + mp8;
            ah[mtw] = *(const bh8*)(Ap + off);
            am[mtw] = *(const bh8*)(Ap + APL + off);
            al[mtw] = *(const bh8*)(Ap + 2 * APL + off);
        }
        bh8 bh[NTW], bm[NTW], bl[NTW];
        #pragma unroll
        for (int nl = 0; nl < NTW; ++nl) { bh[nl] = nbh[nl]; bm[nl] = nbm[nl]; bl[nl] = nbl[nl]; }
        if (kc + 1 < KC) {
            #pragma unroll
            for (int nl = 0; nl < NTW; ++nl) {
                const int fo = (((kc + 1) * 16 + ntoff + nl) * 64 + lane) * 8;
                nbh[nl] = *(const bh8*)(Wp + fo);
                nbm[nl] = *(const bh8*)(Wp + WPL + fo);
                nbl[nl] = *(const bh8*)(Wp + 2 * WPL + fo);
            }
        }
        __builtin_amdgcn_sched_barrier(GEMM_FENCE);
        #pragma unroll
        for (int nl = 0; nl < NTW; ++nl)
            #pragma unroll
            for (int mtw = 0; mtw < MTW; ++mtw) {
                acc[mtw][nl] = __builtin_amdgcn_mfma_f32_16x16x32_bf16(ah[mtw], bl[nl], acc[mtw][nl], 0, 0, 0);
                acc[mtw][nl] = __builtin_amdgcn_mfma_f32_16x16x32_bf16(am[mtw], bm[nl], acc[mtw][nl], 0, 0, 0);
                acc[mtw][nl] = __builtin_amdgcn_mfma_f32_16x16x32_bf16(al[mtw], bh[nl], acc[mtw][nl], 0, 0, 0);
                acc[mtw][nl] = __builtin_amdgcn_mfma_f32_16x16x32_bf16(ah[mtw], bm[nl], acc[mtw][nl], 0, 0, 0);
                acc[mtw][nl] = __builtin_amdgcn_mfma_f32_16x16x32_bf16(am[mtw], bh[nl], acc[mtw][nl], 0, 0, 0);
                acc[mtw][nl] = __builtin_amdgcn_mfma_f32_16x16x32_bf16(ah[mtw], bh[nl], acc[mtw][nl], 0, 0, 0);
            }
    }
}

// ---------------------------------------------------------------------------
// Fused weight prep (unchanged).
// ---------------------------------------------------------------------------
__global__ void prep_all(const float* __restrict__ We, ush* __restrict__ EWp,
                         const float* __restrict__ Ws1, ush* __restrict__ Ws1p,
                         const float* __restrict__ Wc1, ush* __restrict__ Wc1p,
                         const float* __restrict__ W1, ush* __restrict__ W1p,
                         const float* __restrict__ W2, ush* __restrict__ W2p2,
                         const float* __restrict__ b2,
                         const float* __restrict__ Wg, const float* __restrict__ bg,
                         float* __restrict__ Wg2, float* __restrict__ bg2,
                         int* __restrict__ counts)
{
    const int blk = blockIdx.x;
    if (blk < 1024) {                       // expert weights, 2-plane
        const int gid = blk * 256 + threadIdx.x;
        const int nn = gid & 15, nt = (gid >> 4) & 15, qd = (gid >> 8) & 3;
        const int kc = (gid >> 10) & 7, el = gid >> 13;
        const int n = nt * 16 + nn;
        const float* src = We + (size_t)el * 65536 + (size_t)(kc * 32 + qd * 8) * 256 + n;
        union { ush u[8]; bh8 v; } H, L;
        #pragma unroll
        for (int j = 0; j < 8; ++j) bfsplit(src[j * 256], H.u[j], L.u[j]);
        ush* d = EWp + (size_t)el * 131072 + (size_t)((kc * 16 + nt) * 64 + qd * 16 + nn) * 8;
        *(bh8*)d = H.v;
        *(bh8*)(d + 65536) = L.v;
    } else if (blk < 1058) {                // head weights, 2-plane
        const int isC = blk >= 1040;
        const int gid = (isC ? blk - 1040 : blk - 1024) * 256 + threadIdx.x;
        const int KC = isC ? 9 : 8, Kreal = isC ? 283 : 256;
        if (gid >= KC * 512) return;
        const float* W = isC ? Wc1 : Ws1;
        ush* dst = isC ? Wc1p : Ws1p;
        const int nn = gid & 15, nt = (gid >> 4) & 7, qd = (gid >> 7) & 3, kc = gid >> 9;
        const int n = nt * 16 + nn;
        union { ush u[8]; bh8 v; } H, L;
        #pragma unroll
        for (int j = 0; j < 8; ++j) {
            const int k = kc * 32 + qd * 8 + j;
            const float x = (k < Kreal) ? W[k * 128 + n] : 0.f;
            bfsplit(x, H.u[j], L.u[j]);
        }
        ush* d = dst + (size_t)((kc * 8 + nt) * 64 + qd * 16 + nn) * 8;
        *(bh8*)d = H.v;
        *(bh8*)(d + KC * 4096) = L.v;
    } else if (blk < 1066) {                // trunk W1, 3-plane
        const int gid = (blk - 1058) * 256 + threadIdx.x;
        const int KC = 2, Kreal = 63;
        const int n15 = gid & 15, qd = (gid >> 4) & 3, nt = (gid >> 6) & 15, kc = gid >> 10;
        const int n = nt * 16 + n15;
        const int plane = KC * 8192;
        union { ush u[8]; bh8 v; } H, M, L;
        #pragma unroll
        for (int j = 0; j < 8; ++j) {
            const int k = kc * 32 + qd * 8 + j;
            const float x = (k < Kreal) ? W1[k * 256 + n] : 0.f;
            bfsplit3(x, H.u[j], M.u[j], L.u[j]);
        }
        ush* d = W1p + (size_t)gid * 8;
        *(bh8*)d = H.v;
        *(bh8*)(d + plane) = M.v;
        *(bh8*)(d + 2 * plane) = L.v;
    } else if (blk < 1098) {                // trunk W2, 2-plane
        const int gid = (blk - 1066) * 256 + threadIdx.x;
        const int KC = 8;
        const int n15 = gid & 15, qd = (gid >> 4) & 3, nt = (gid >> 6) & 15, kc = gid >> 10;
        const int n = nt * 16 + n15;
        const int plane = KC * 8192;
        union { ush u[8]; bh8 v; } H, L;
        #pragma unroll
        for (int j = 0; j < 8; ++j) {
            const int k = kc * 32 + qd * 8 + j;
            bfsplit(W2[k * 256 + n], H.u[j], L.u[j]);
        }
        ush* d = W2p2 + (size_t)gid * 8;
        *(bh8*)d = H.v;
        *(bh8*)(d + plane) = L.v;
    } else if (blk < 1106) {                // fused gate: Wg2 = W2@Wg, bg2
        const int gid = (blk - 1098) * 256 + threadIdx.x;
        const int k = gid >> 3, e = gid & 7;
        float s = 0.f;
        for (int j = 0; j < HD; ++j) s += W2[k * HD + j] * Wg[j * NE + e];
        Wg2[k * NE + e] = s;
        if (gid < NE) {
            float t = bg[gid];
            for (int j = 0; j < HD; ++j) t += b2[j] * Wg[j * NE + gid];
            bg2[gid] = t;
        }
    } else {                                // counts zeroing
        if (threadIdx.x < NE) counts[threadIdx.x] = 0;
    }
}

// ---------------------------------------------------------------------------
// Kernel 1: posenc -> l1 (3-plane 6-term) -> l2 (2-plane 3-term) -> fused gate
// + bucket. 32 rows/block, 512 thr, 2 blocks/CU.
// ---------------------------------------------------------------------------
__global__ void __attribute__((amdgpu_flat_work_group_size(512, 512), amdgpu_waves_per_eu(4, 4)))
trunk_kernel(
    const float* __restrict__ xyz,
    const ush* __restrict__ W1p, const float* __restrict__ b1,
    const ush* __restrict__ W2p2, const float* __restrict__ b2,
    const float* __restrict__ Wg2, const float* __restrict__ bg2,
    unsigned* __restrict__ h2p, float* __restrict__ gateout,
    int* __restrict__ counts, int* __restrict__ bucket)
{
    __shared__ ush   exP[3 * 2048];   // posenc 3 planes (KC=2, MT=2); later gate partials
    __shared__ ush   h1h[8192];       // h1 hi plane (KC=8, MT=2)
    __shared__ ush   h1l[8192];       // h1 lo plane
    __shared__ float h1f[32 * 259];   // h1 fp32 (gate path)
    __shared__ int   lcount[NE], lbase[NE], lpos[32], lexp[32];

    const int tid  = threadIdx.x;
    const int row0 = blockIdx.x * 32;
    const int lane = tid & 63, wv = tid >> 6;
    const int q = lane >> 4, n15 = lane & 15;
    if (tid < NE) lcount[tid] = 0;

    {   // posenc: thread (row, g) writes 4 k's
        const int row = tid & 31, g = tid >> 5;
        const int i = row0 + row;
        const float xv[3] = {xyz[3 * i], xyz[3 * i + 1], xyz[3 * i + 2]};
        const int mt = row >> 4, m = row & 15;
        const int mp8 = rowperm(m) * 8;
        #pragma unroll
        for (int kk = 0; kk < 4; ++kk) {
            const int k = g * 4 + kk;
            float v = 0.f;
            if (k < 3) v = xv[k];
            else if (k < 63) {
                const int l = (k - 3) / 6, c = (k - 3) % 6;
                const float f = (float)(1 << l);
                v = (c < 3) ? sinf(f * xv[c]) : cosf(f * xv[c - 3]);
            }
            const int kc = k >> 5, qq = (k >> 3) & 3, j = k & 7;
            const int off = ((kc * 2 + mt) * 4 + qq) * 128 + mp8 + j;
            ush hh, mm, ll; split3t(v, hh, mm, ll);
            exP[off] = hh; exP[2048 + off] = mm; exP[4096 + off] = ll;
        }
    }
    // l1's kc=0 B (3 planes) prefetch: issued after posenc, rides the barrier
    bh8 p3h[2], p3m[2], p3l[2];
    loadB0_3<2>(W1p, 2 * 8192, lane, wv * 2, p3h, p3m, p3l);
    lds_barrier();

    bh8 pbh[2], pbl[2];   // l2's B0 ring

    // --- l1 = relu(ex @ W1 + b1): 6-term; store fp32 (gate) + 2-plane (l2) ---
    {
        f4 acc[2][2];
        #pragma unroll
        for (int a = 0; a < 2; ++a)
            #pragma unroll
            for (int b_ = 0; b_ < 2; ++b_) acc[a][b_] = (f4){0.f, 0.f, 0.f, 0.f};
        gemm3<2, 2, 2, 2>(exP, W1p, lane, 0, wv * 2, acc, p3h, p3m, p3l);
        loadB0<2>(W2p2, W2p2 + 65536, lane, wv * 2, pbh, pbl);   // l2 B0 in flight
        #pragma unroll
        for (int nl = 0; nl < 2; ++nl) {
            const int col = wv * 32 + nl * 16 + n15;
            const float bias = b1[col];
            const int kc = col >> 5, qc = (col >> 3) & 3, jc = col & 7;
            #pragma unroll
            for (int mt = 0; mt < 2; ++mt)
                #pragma unroll
                for (int r = 0; r < 4; ++r) {
                    const int row = mt * 16 + q * 4 + r;
                    const float v = fmaxf(acc[mt][nl][r] + bias, 0.f);
                    const int off = ((kc * 2 + mt) * 4 + qc) * 128 + (q * 4 + (r ^ q)) * 8 + jc;
                    ush hh, ll; split2t(v, hh, ll);
                    h1h[off] = hh; h1l[off] = ll;
                    h1f[row * 259 + col] = v;
                }
        }
    }
    lds_barrier();

    // --- l2 = h1 @ W2 + b2: 2-plane 3-term; epilogue straight to global ---
    {
        f4 acc[2][2];
        #pragma unroll
        for (int a = 0; a < 2; ++a)
            #pragma unroll
            for (int b_ = 0; b_ < 2; ++b_) acc[a][b_] = (f4){0.f, 0.f, 0.f, 0.f};
        gemm2p<8, 2, 16, 2, 2>(h1h, h1l, W2p2, W2p2 + 65536, lane, 0, wv * 2, acc, pbh, pbl);
        lds_barrier();   // all h1h/h1l reads done before part overlay
        #pragma unroll
        for (int nl = 0; nl < 2; ++nl) {
            const int col = wv * 32 + nl * 16 + n15;
            const float bias = b2[col];
            #pragma unroll
            for (int mt = 0; mt < 2; ++mt)
                #pragma unroll
                for (int r = 0; r < 4; ++r) {
                    const int row = mt * 16 + q * 4 + r;
                    h2p[(size_t)(row0 + row) * HD + col] = pack2t(acc[mt][nl][r] + bias);
                }
        }
    }

    // --- gate partials from h1f via fused Wg2 (h1f stable; exP dead) ---
    float* part = (float*)exP;        // [8][32][8]
    if (tid < 256) {
        const int row = tid & 31, seg = tid >> 5, k0 = seg * 32;
        float lg[NE];
        #pragma unroll
        for (int e = 0; e < NE; ++e) lg[e] = 0.f;
        for (int k = k0; k < k0 + 32; ++k) {
            const float hv = h1f[row * 259 + k];
            const float4 w0 = *(const float4*)(Wg2 + k * 8);
            const float4 w1 = *(const float4*)(Wg2 + k * 8 + 4);
            lg[0] = fmaf(hv, w0.x, lg[0]); lg[1] = fmaf(hv, w0.y, lg[1]);
            lg[2] = fmaf(hv, w0.z, lg[2]); lg[3] = fmaf(hv, w0.w, lg[3]);
            lg[4] = fmaf(hv, w1.x, lg[4]); lg[5] = fmaf(hv, w1.y, lg[5]);
            lg[6] = fmaf(hv, w1.z, lg[6]); lg[7] = fmaf(hv, w1.w, lg[7]);
        }
        #pragma unroll
        for (int e = 0; e < NE; ++e) part[(seg * 32 + row) * 8 + e] = lg[e];
    }
    lds_barrier();

    if (tid < 32) {
        float lg[NE];
        #pragma unroll
        for (int e = 0; e < NE; ++e) {
            float s = bg2[e];
            #pragma unroll
            for (int sg = 0; sg < 8; ++sg) s += part[(sg * 32 + tid) * 8 + e];
            lg[e] = s;
        }
        int best = 0; float mx = lg[0];
        #pragma unroll
        for (int e = 1; e < NE; ++e) if (lg[e] > mx) { mx = lg[e]; best = e; }
        float s = 0.f;
        #pragma unroll
        for (int e = 0; e < NE; ++e) s += expf(lg[e] - mx);
        gateout[row0 + tid] = 1.f / s;
        lexp[tid] = best;
        lpos[tid] = atomicAdd(&lcount[best], 1);
    }
    lds_barrier();
    if (tid < NE) lbase[tid] = atomicAdd(&counts[tid], lcount[tid]);
    lds_barrier();
    if (tid < 32) {
        const int e = lexp[tid];
        bucket[e * NS + lbase[e] + lpos[tid]] = row0 + tid;
    }
}

// ---------------------------------------------------------------------------
// Kernel 2: expert MLP + heads. 64 rows, 8 waves all-M MT=4, NTW=2; LDS 78KB
// -> 2 blocks/CU. R7's XCD-pin (e = blk&7) REVERTED: it made weights
// L2-resident (FETCH 93->64MB) but serialized each expert onto one XCD ->
// per-XCD load imbalance, occupancy 29%->13%, dur 149->322. Work spread
// across all CUs dominates weight locality here. Depth-2 B ring kept.
// ---------------------------------------------------------------------------
__global__ void __attribute__((amdgpu_flat_work_group_size(512, 512), amdgpu_waves_per_eu(4, 4)))
expert_kernel(
    const unsigned* __restrict__ h2p, const float* __restrict__ gatebuf,
    const int* __restrict__ counts, const int* __restrict__ bucket,
    const ush* __restrict__ EWp, const float* __restrict__ be,
    const float* __restrict__ dirs,
    const ush* __restrict__ Ws1p, const float* __restrict__ bs1,
    const float* __restrict__ Ws2, const float* __restrict__ bs2,
    const ush* __restrict__ Wc1p, const float* __restrict__ bc1,
    const float* __restrict__ Wc2, const float* __restrict__ bc2,
    float* __restrict__ outp)
{
    __shared__ ush   Ah[9 * 2048];      // hi plane (KC=9 incl. dirs ext); later fp32 s
    __shared__ ush   Al[9 * 2048];      // lo plane;                       later fp32 c
    __shared__ float dotp[4 * 64 * 4];
    __shared__ int   idx[64];
    __shared__ float gatev[64];

    const int tid = threadIdx.x;
    const int e   = blockIdx.x >> 10;
    const int t   = blockIdx.x & 1023;
    const int cnt = counts[e];
    if (t * 64 >= cnt) return;
    const int nact = min(64, cnt - t * 64);

    const int lane = tid & 63, wv = tid >> 6;
    const int q = lane >> 4, n15 = lane & 15;

    const float* bb = be + e * 4 * HD;
    const ush* W0 = EWp + (size_t)(e * 4) * 131072;

    // l0 B0 prefetch: in flight across idx load + gather + barrier
    bh8 pbh[2], pbl[2];
    loadB0<2>(W0, W0 + 65536, lane, wv * 2, pbh, pbl);

    if (tid < 64) {
        const int src = bucket[e * NS + t * 64 + min(tid, nact - 1)];
        idx[tid]   = src;
        gatev[tid] = gatebuf[src];
    }
    lds_barrier();

    {   // gather: wave wv -> kc=wv, lane = row; unpack packed h2 into planes
        const int row = lane, mt = row >> 4, m = row & 15;
        const int mp8 = rowperm(m) * 8;
        const unsigned* src = h2p + (size_t)idx[row] * HD + wv * 32;
        #pragma unroll
        for (int sub = 0; sub < 4; ++sub) {
            bh8 hv, lv;
            unpack8(src + sub * 8, hv, lv);
            const int off = ((wv * 4 + mt) * 4 + sub) * 128 + mp8;
            *(bh8*)(Ah + off) = hv;
            *(bh8*)(Al + off) = lv;
        }
    }
    if (tid < 64) {   // dirs posenc ext -> kc=8 region
        const int row = tid, i = idx[row];
        const int mt = row >> 4, m = row & 15;
        const int mp8 = rowperm(m) * 8;
        const float d0 = dirs[3 * i], d1 = dirs[3 * i + 1], d2 = dirs[3 * i + 2];
        float vals[32];
        vals[0] = d0; vals[1] = d1; vals[2] = d2;
        float f = 1.f;
        #pragma unroll
        for (int l = 0; l < 4; ++l) {
            vals[3 + 6 * l + 0] = sinf(f * d0);
            vals[3 + 6 * l + 1] = sinf(f * d1);
            vals[3 + 6 * l + 2] = sinf(f * d2);
            vals[3 + 6 * l + 3] = cosf(f * d0);
            vals[3 + 6 * l + 4] = cosf(f * d1);
            vals[3 + 6 * l + 5] = cosf(f * d2);
            f *= 2.f;
        }
        #pragma unroll
        for (int c = 27; c < 32; ++c) vals[c] = 0.f;
        #pragma unroll
        for (int k2 = 0; k2 < 32; ++k2) {
            const int off = ((8 * 4 + mt) * 4 + (k2 >> 3)) * 128 + mp8 + (k2 & 7);
            ush hh, ll; split2t(vals[k2], hh, ll);
            Ah[off] = hh; Al[off] = ll;
        }
    }
    lds_barrier();

    // ---- l0: A <- relu(A @ W0 + b0); capture skip (old A) into l1's acc ----
    f4 acc1[4][2];   // l1 accumulator, seeded with the skip values
    {
        f4 acc[4][2];
        #pragma unroll
        for (int mt = 0; mt < 4; ++mt)
            #pragma unroll
            for (int nl = 0; nl < 2; ++nl) acc[mt][nl] = (f4){0.f, 0.f, 0.f, 0.f};
        gemm2p<8, 2, 16, 4, 4>(Ah, Al, W0, W0 + 65536, lane, 0, wv * 2, acc, pbh, pbl);
        loadB0<2>(W0 + 131072, W0 + 131072 + 65536, lane, wv * 2, pbh, pbl);   // l1 B0
        lds_barrier();
        #pragma unroll
        for (int nl = 0; nl < 2; ++nl) {
            const int col = wv * 32 + nl * 16 + n15;
            const float bias = bb[col];
            const int kc = col >> 5, qc = (col >> 3) & 3, jc = col & 7;
            #pragma unroll
            for (int mt = 0; mt < 4; ++mt)
                #pragma unroll
                for (int r = 0; r < 4; ++r) {
                    const int off = ((kc * 4 + mt) * 4 + qc) * 128 + (q * 4 + (r ^ q)) * 8 + jc;
                    // capture old value (= h2[row][col], the l1 skip) before overwrite
                    acc1[mt][nl][r] = planes2f(Ah[off], Al[off]);
                    const float v = fmaxf(acc[mt][nl][r] + bias, 0.f);
                    ush hh, ll; split2t(v, hh, ll);
                    Ah[off] = hh; Al[off] = ll;
                }
        }
        lds_barrier();
    }
    // ---- l1: A <- relu(A @ W1 + b1 + skip); skip pre-seeded in acc1 ----
    {
        gemm2p<8, 2, 16, 4, 4>(Ah, Al, W0 + 131072, W0 + 131072 + 65536, lane, 0, wv * 2, acc1, pbh, pbl);
        loadB0<2>(W0 + 2 * 131072, W0 + 2 * 131072 + 65536, lane, wv * 2, pbh, pbl);   // l2 B0
        lds_barrier();
        #pragma unroll
        for (int nl = 0; nl < 2; ++nl) {
            const int col = wv * 32 + nl * 16 + n15;
            const float bias = bb[256 + col];
            const int kc = col >> 5, qc = (col >> 3) & 3, jc = col & 7;
            #pragma unroll
            for (int mt = 0; mt < 4; ++mt)
                #pragma unroll
                for (int r = 0; r < 4; ++r) {
                    const int off = ((kc * 4 + mt) * 4 + qc) * 128 + (q * 4 + (r ^ q)) * 8 + jc;
                    const float v = fmaxf(acc1[mt][nl][r] + bias, 0.f);
                    ush hh, ll; split2t(v, hh, ll);
                    Ah[off] = hh; Al[off] = ll;
                }
        }
        lds_barrier();
    }
    // ---- l2: A <- relu(A @ W2 + b2) ----
    {
        f4 acc[4][2];
        #pragma unroll
        for (int mt = 0; mt < 4; ++mt)
            #pragma unroll
            for (int nl = 0; nl < 2; ++nl) acc[mt][nl] = (f4){0.f, 0.f, 0.f, 0.f};
        gemm2p<8, 2, 16, 4, 4>(Ah, Al, W0 + 2 * 131072, W0 + 2 * 131072 + 65536, lane, 0, wv * 2, acc, pbh, pbl);
        loadB0<2>(W0 + 3 * 131072, W0 + 3 * 131072 + 65536, lane, wv * 2, pbh, pbl);   // l3 B0
        lds_barrier();
        #pragma unroll
        for (int nl = 0; nl < 2; ++nl) {
            const int col = wv * 32 + nl * 16 + n15;
            const float bias = bb[512 + col];
            const int kc = col >> 5, qc = (col >> 3) & 3, jc = col & 7;
            #pragma unroll
            for (int mt = 0; mt < 4; ++mt)
                #pragma unroll
                for (int r = 0; r < 4; ++r) {
                    const int off = ((kc * 4 + mt) * 4 + qc) * 128 + (q * 4 + (r ^ q)) * 8 + jc;
                    const float v = fmaxf(acc[mt][nl][r] + bias, 0.f);
                    ush hh, ll; split2t(v, hh, ll);
                    Ah[off] = hh; Al[off] = ll;
                }
        }
        lds_barrier();
    }
    // ---- l3: A <- gate * (A @ W3 + b3)  (no relu) ----
    bh8 sb0h, sb0l, cb0h, cb0l;   // heads kc=0 B prefetch
    {
        f4 acc[4][2];
        #pragma unroll
        for (int mt = 0; mt < 4; ++mt)
            #pragma unroll
            for (int nl = 0; nl < 2; ++nl) acc[mt][nl] = (f4){0.f, 0.f, 0.f, 0.f};
        gemm2p<8, 2, 16, 4, 4>(Ah, Al, W0 + 3 * 131072, W0 + 3 * 131072 + 65536, lane, 0, wv * 2, acc, pbh, pbl);
        {
            const int fo = (wv * 64 + lane) * 8;
            sb0h = *(const bh8*)(Ws1p + fo);
            sb0l = *(const bh8*)(Ws1p + 32768 + fo);
            cb0h = *(const bh8*)(Wc1p + fo);
            cb0l = *(const bh8*)(Wc1p + 36864 + fo);
        }
        lds_barrier();
        #pragma unroll
        for (int nl = 0; nl < 2; ++nl) {
            const int col = wv * 32 + nl * 16 + n15;
            const float bias = bb[768 + col];
            const int kc = col >> 5, qc = (col >> 3) & 3, jc = col & 7;
            #pragma unroll
            for (int mt = 0; mt < 4; ++mt)
                #pragma unroll
                for (int r = 0; r < 4; ++r) {
                    const int row = mt * 16 + q * 4 + r;
                    const int off = ((kc * 4 + mt) * 4 + qc) * 128 + (q * 4 + (r ^ q)) * 8 + jc;
                    const float v = gatev[row] * (acc[mt][nl][r] + bias);
                    ush hh, ll; split2t(v, hh, ll);
                    Ah[off] = hh; Al[off] = ll;
                }
        }
        lds_barrier();
    }

    // ---- heads (fused): s = relu(out@Ws1+bs1), c = relu([out,ed]@Wc1+bc1) ----
    {
        f4 sacc[4], cacc[4];
        #pragma unroll
        for (int mt = 0; mt < 4; ++mt) {
            sacc[mt] = (f4){0.f, 0.f, 0.f, 0.f};
            cacc[mt] = (f4){0.f, 0.f, 0.f, 0.f};
        }
        gemm_heads<4, 4>(Ah, Al, Ws1p, Ws1p + 32768, Wc1p, Wc1p + 36864,
                         lane, 0, wv, sacc, cacc, sb0h, sb0l, cb0h, cb0l);
        lds_barrier();
        float* sp = (float*)Ah;          // [64][133]
        float* cp = (float*)Al;
        const int col = wv * 16 + n15;
        const float b_s = bs1[col], b_c = bc1[col];
        #pragma unroll
        for (int mt = 0; mt < 4; ++mt)
            #pragma unroll
            for (int r = 0; r < 4; ++r) {
                const int row = mt * 16 + q * 4 + r;
                sp[row * 133 + col] = fmaxf(sacc[mt][r] + b_s, 0.f);
                cp[row * 133 + col] = fmaxf(cacc[mt][r] + b_c, 0.f);
            }
        lds_barrier();
    }
    // ---- final dots: 4 segs x 64 rows, 32 k each ----
    if (tid < 256) {
        const float* sp = (const float*)Ah;
        const float* cp = (const float*)Al;
        const int row = tid & 63, seg = tid >> 6, k0 = seg * 32;
        float ps = 0.f, p0 = 0.f, p1 = 0.f, p2 = 0.f;
        for (int k = k0; k < k0 + 32; ++k) {
            ps = fmaf(sp[row * 133 + k], Ws2[k], ps);
            const float cv = cp[row * 133 + k];
            p0 = fmaf(cv, Wc2[3 * k + 0], p0);
            p1 = fmaf(cv, Wc2[3 * k + 1], p1);
            p2 = fmaf(cv, Wc2[3 * k + 2], p2);
        }
        *(float4*)&dotp[(seg * 64 + row) * 4] = make_float4(ps, p0, p1, p2);
    }
    lds_barrier();
    if (tid < nact) {
        float sg = bs2[0], r0 = bc2[0], r1 = bc2[1], r2 = bc2[2];
        #pragma unroll
        for (int s2 = 0; s2 < 4; ++s2) {
            const float4 pv = *(const float4*)&dotp[(s2 * 64 + tid) * 4];
            sg += pv.x; r0 += pv.y; r1 += pv.z; r2 += pv.w;
        }
        float4 o;
        o.x = 1.f / (1.f + expf(-r0));
        o.y = 1.f / (1.f + expf(-r1));
        o.z = 1.f / (1.f + expf(-r2));
        o.w = fmaxf(sg, 0.f) + log1pf(expf(-fabsf(sg)));
        *(float4*)&outp[(size_t)idx[tid] * 4] = o;
    }
}

// ---------------------------------------------------------------------------
extern "C" void kernel_launch(void* const* d_in, const int* in_sizes, int n_in,
                              void* d_out, int out_size, void* d_ws, size_t ws_size,
                              hipStream_t stream)
{
    const float* xyz  = (const float*)d_in[0];
    const float* dirs = (const float*)d_in[1];
    const float* W1   = (const float*)d_in[2];
    const float* b1   = (const float*)d_in[3];
    const float* W2   = (const float*)d_in[4];
    const float* b2   = (const float*)d_in[5];
    const float* Wg   = (const float*)d_in[6];
    const float* bg   = (const float*)d_in[7];
    const float* We   = (const float*)d_in[8];
    const float* be   = (const float*)d_in[9];
    const float* Ws1  = (const float*)d_in[10];
    const float* bs1  = (const float*)d_in[11];
    const float* Ws2  = (const float*)d_in[12];
    const float* bs2  = (const float*)d_in[13];
    const float* Wc1  = (const float*)d_in[14];
    const float* bc1  = (const float*)d_in[15];
    const float* Wc2  = (const float*)d_in[16];
    const float* bc2  = (const float*)d_in[17];
    float* out = (float*)d_out;

    char* ws = (char*)d_ws;
    unsigned* h2p     = (unsigned*)ws;                        // 64 MB packed h2
    float*    gatebuf = (float*)(ws + 67108864);              // 256 KB
    int*      counts  = (int*)(ws + 67371008);                // 1 KB (padded)
    int*      bucket  = (int*)(ws + 67372032);                // 2 MB
    ush*      EWp     = (ush*)(ws + 69469184);                // 8 MB expert frags
    ush*      Ws1p    = (ush*)(ws + 77857792);                // 128 KB
    ush*      Wc1p    = (ush*)(ws + 77988864);                // 144 KB
    ush*      W1p     = (ush*)(ws + 78136320);                // 96 KB  (3 planes)
    ush*      W2p2    = (ush*)(ws + 78234624);                // 256 KB (2 planes)
    float*    Wg2     = (float*)(ws + 78496768);              // 8 KB
    float*    bg2     = (float*)(ws + 78504960);              // 32 B

    prep_all<<<1107, 256, 0, stream>>>(We, EWp, Ws1, Ws1p, Wc1, Wc1p,
                                       W1, W1p, W2, W2p2, b2, Wg, bg,
                                       Wg2, bg2, counts);
    trunk_kernel<<<NS / 32, 512, 0, stream>>>(xyz, W1p, b1, W2p2, b2, Wg2, bg2,
                                              h2p, gatebuf, counts, bucket);
    expert_kernel<<<NE * 1024, 512, 0, stream>>>(h2p, gatebuf, counts, bucket,
                                                 EWp, be, dirs, Ws1p, bs1, Ws2, bs2,
                                                 Wc1p, bc1, Wc2, bc2, out);
}